// Round 16
// baseline (78.382 us; speedup 1.0000x reference)
//
#include <hip/hip_runtime.h>

#define NTOK 16384
#define TB 8

typedef float f32x4_t __attribute__((ext_vector_type(4)));
typedef short s16x8_t __attribute__((ext_vector_type(8)));

union bfpack { unsigned int u[4]; s16x8_t v; };

__device__ __forceinline__ unsigned int pk2bf(float lo, float hi) {
    unsigned int r;
    asm("v_cvt_pk_bf16_f32 %0, %1, %2" : "=v"(r) : "v"(lo), "v"(hi));
    return r;
}
__device__ __forceinline__ unsigned short f2bf(float f) {
    unsigned int r;
    asm("v_cvt_pk_bf16_f32 %0, %1, %1" : "=v"(r) : "v"(f));
    return (unsigned short)r;
}
__device__ __forceinline__ unsigned short f2bf_host_style(float f) {
    unsigned int x = __float_as_uint(f);
    x += 0x7fffu + ((x >> 16) & 1u);
    return (unsigned short)(x >> 16);
}
__device__ __forceinline__ float fexp2(float x) {
#if __has_builtin(__builtin_amdgcn_exp2f)
    return __builtin_amdgcn_exp2f(x);
#else
    return exp2f(x);
#endif
}
__device__ __forceinline__ float frcp(float x) {
#if __has_builtin(__builtin_amdgcn_rcpf)
    return __builtin_amdgcn_rcpf(x);
#else
    return 1.0f / x;
#endif
}
__device__ __forceinline__ float frsq(float x) {
#if __has_builtin(__builtin_amdgcn_rsqf)
    return __builtin_amdgcn_rsqf(x);
#else
    return rsqrtf(x);
#endif
}

// ---- prep (R9/R10/R12-proven, unchanged): W1T [m][k] + attn weights in fragment order ----
// ushort off within matrix = hk*2048 + tile*512 + l*8 + e
//   holds W[k = hk*32 + (l>>4)*8 + e][m = tile*16 + (l&15)]
__global__ __launch_bounds__(256)
void prep_kernel(const float* __restrict__ W1,
                 const float* __restrict__ Wq, const float* __restrict__ Wk,
                 const float* __restrict__ Wv, const float* __restrict__ Wf1,
                 const float* __restrict__ Wf2, unsigned short* __restrict__ wsb)
{
    const int i = blockIdx.x * 256 + threadIdx.x;
    if (i < 16384) {
        const int m = i >> 8, k = i & 255;
        wsb[i] = f2bf_host_style(W1[k * 64 + m]);
    } else if (i < 77824) {
        const int u  = i - 16384;
        const int mi = u >> 12;            // matrix 0..14
        const int st = mi / 5, q = mi % 5;
        const int r  = u & 4095;
        const int hk = r >> 11;
        const int r1 = r & 2047;
        const int w  = r1 >> 9;
        const int r2 = r1 & 511;
        const int l  = r2 >> 3;
        const int e  = r2 & 7;
        const int m  = w * 16 + (l & 15);
        const int k  = hk * 32 + (l >> 4) * 8 + e;
        const float* src = q == 0 ? Wq : q == 1 ? Wk : q == 2 ? Wv : q == 3 ? Wf1 : Wf2;
        wsb[i] = f2bf_host_style(src[st * 4096 + k * 64 + m]);
    }
}

// 128-thread blocks (2 waves): shared GEMMs, each wave owns 2 col-tiles.
// Small sync domain + 8 independent blocks/CU.
__global__ __launch_bounds__(128, 4)
void tf3_kernel(const float* __restrict__ x,
                const float* __restrict__ b1,
                const float* __restrict__ bq, const float* __restrict__ bk,
                const float* __restrict__ bv,
                const float* __restrict__ bf1, const float* __restrict__ bf2,
                const float* __restrict__ lng, const float* __restrict__ lnb,
                const float* __restrict__ Wout, const float* __restrict__ bout,
                const unsigned short* __restrict__ wsb,
                float* __restrict__ out)
{
    // LDS 15104 B: a_lds[16][64]u16 | q[16][68]f32 | ky | v. x_img (8KB) aliases q∪ky.
    __shared__ __align__(16) char smem[15104];
    unsigned short* a_lds = (unsigned short*)smem;
    float* q_lds  = (float*)(smem + 2048);
    float* ky_lds = (float*)(smem + 6400);
    float* v_lds  = (float*)(smem + 10752);
    char*  x_img  = smem + 2048;

    const int tid = threadIdx.x;
    const int wv  = tid >> 6;        // wave 0..1
    const int l   = tid & 63;
    const int n0  = blockIdx.x * TB;

    const int lr  = l & 15;
    const int q4  = l >> 4;
    const int c0  = wv * 32 + lr;    // wave's first col-tile column
    const int c1  = c0 + 16;         // second col-tile column

    float res_reg[4], cur_reg[4];

    // fragment loads for the wave's 2 col-tiles (T0 = wv*2, T1 = wv*2+1), both k-halves
    auto LOADM2 = [&](int mat, s16x8_t& a00, s16x8_t& a01, s16x8_t& a10, s16x8_t& a11) {
        const char* gb = (const char*)(wsb + 16384) + mat * 8192 + (wv * 2) * 1024 + l * 16;
        a00 = *reinterpret_cast<const s16x8_t*>(gb);            // kh0, T0
        a10 = *reinterpret_cast<const s16x8_t*>(gb + 1024);     // kh0, T1
        a01 = *reinterpret_cast<const s16x8_t*>(gb + 4096);     // kh1, T0
        a11 = *reinterpret_cast<const s16x8_t*>(gb + 4096 + 1024); // kh1, T1
    };

    s16x8_t bq00, bq01, bq10, bq11;
    s16x8_t bk00, bk01, bk10, bk11;
    s16x8_t bv00, bv01, bv10, bv11;
    s16x8_t f100, f101, f110, f111;
    s16x8_t f200, f201, f210, f211;

    LOADM2(0, bq00, bq01, bq10, bq11);
    LOADM2(1, bk00, bk01, bk10, bk11);
    LOADM2(2, bv00, bv01, bv10, bv11);

    // ---- shared x-convert: 8 rows x 256 cols, 16 floats/thread -> swizzled image ----
    {
        const int r  = tid >> 4;           // row 0..7
        const int cb = tid & 15;           // 16-col block
        const float* xp = x + (size_t)(n0 + r) * 256 + cb * 16;
        const float4 u0 = *reinterpret_cast<const float4*>(xp);
        const float4 u1 = *reinterpret_cast<const float4*>(xp + 4);
        const float4 u2 = *reinterpret_cast<const float4*>(xp + 8);
        const float4 u3 = *reinterpret_cast<const float4*>(xp + 12);
        bfpack P0, P1;
        P0.u[0] = pk2bf(u0.x, u0.y); P0.u[1] = pk2bf(u0.z, u0.w);
        P0.u[2] = pk2bf(u1.x, u1.y); P0.u[3] = pk2bf(u1.z, u1.w);
        P1.u[0] = pk2bf(u2.x, u2.y); P1.u[1] = pk2bf(u2.z, u2.w);
        P1.u[2] = pk2bf(u3.x, u3.y); P1.u[3] = pk2bf(u3.z, u3.w);
        char* rowb = x_img + r * 512;
        *reinterpret_cast<s16x8_t*>(rowb + (((cb * 2    ) ^ (r & 7)) << 4)) = P0.v;
        *reinterpret_cast<s16x8_t*>(rowb + (((cb * 2 + 1) ^ (r & 7)) << 4)) = P1.v;
    }
    __syncthreads();                       // B0a

    // ---- stage 0: h = x @ W1 + b1 (A from x-image, B direct global W1T) ----
    f32x4_t acch0 = {0.f, 0.f, 0.f, 0.f};
    f32x4_t acch1 = {0.f, 0.f, 0.f, 0.f};
    #pragma unroll
    for (int s5 = 0; s5 < 8; ++s5) {
        const s16x8_t af = *reinterpret_cast<const s16x8_t*>(
            x_img + lr * 512 + (((s5 * 4 + q4) ^ (lr & 7)) << 4));
        const s16x8_t bf0 = *reinterpret_cast<const s16x8_t*>(&wsb[c0 * 256 + s5 * 32 + q4 * 8]);
        const s16x8_t bf1f = *reinterpret_cast<const s16x8_t*>(&wsb[c1 * 256 + s5 * 32 + q4 * 8]);
        acch0 = __builtin_amdgcn_mfma_f32_16x16x32_bf16(af, bf0, acch0, 0, 0, 0);
        acch1 = __builtin_amdgcn_mfma_f32_16x16x32_bf16(af, bf1f, acch1, 0, 0, 0);
    }
    __syncthreads();                       // B0mid: x-image consumed (q aliases it)
    {
        const float bb0 = b1[c0];
        const float bb1 = b1[c1];
        #pragma unroll
        for (int rg = 0; rg < 4; ++rg) {
            const int tr = q4 * 4 + rg;
            q_lds[tr * 68 + c0] = acch0[rg] + bb0;
            q_lds[tr * 68 + c1] = acch1[rg] + bb1;
        }
    }
    __syncthreads();                       // B0b
    #pragma unroll
    for (int tt = 0; tt < 4; ++tt) {       // cur = h, res = leaky(h, 0.1); tokens wv*4+tt
        const int t = wv * 4 + tt;
        const float h = q_lds[t * 68 + l];
        cur_reg[tt] = h;
        res_reg[tt] = h >= 0.f ? h : 0.1f * h;
        a_lds[t * 64 + (((l >> 3) ^ (t & 7)) * 8) + (l & 7)] = f2bf(h);
    }

    // ---------------- 3 attention stages ----------------
    for (int st = 0; st < 3; ++st) {
        const float bqv0 = bq[st * 64 + c0], bqv1 = bq[st * 64 + c1];
        const float bkv0 = bk[st * 64 + c0], bkv1 = bk[st * 64 + c1];
        const float bvv0 = bv[st * 64 + c0], bvv1 = bv[st * 64 + c1];
        const float bf1v0 = bf1[st * 64 + c0], bf1v1 = bf1[st * 64 + c1];
        const float bf2v0 = bf2[st * 64 + c0], bf2v1 = bf2[st * 64 + c1];
        const float lngv = lng[st * 64 + l];
        const float lnbv = lnb[st * 64 + l];

        __syncthreads();                   // B1: a_lds ready (both waves' writes)
        {   // QKV: 3 GEMMs, each wave does its 2 col-tiles
            const s16x8_t af0 = *reinterpret_cast<const s16x8_t*>(&a_lds[lr * 64 + ((q4       ^ (lr & 7)) * 8)]);
            const s16x8_t af1 = *reinterpret_cast<const s16x8_t*>(&a_lds[lr * 64 + (((4 + q4) ^ (lr & 7)) * 8)]);
            f32x4_t aq0 = __builtin_amdgcn_mfma_f32_16x16x32_bf16(af0, bq00, (f32x4_t){0.f,0.f,0.f,0.f}, 0, 0, 0);
            aq0 = __builtin_amdgcn_mfma_f32_16x16x32_bf16(af1, bq01, aq0, 0, 0, 0);
            f32x4_t aq1 = __builtin_amdgcn_mfma_f32_16x16x32_bf16(af0, bq10, (f32x4_t){0.f,0.f,0.f,0.f}, 0, 0, 0);
            aq1 = __builtin_amdgcn_mfma_f32_16x16x32_bf16(af1, bq11, aq1, 0, 0, 0);
            f32x4_t ak0 = __builtin_amdgcn_mfma_f32_16x16x32_bf16(af0, bk00, (f32x4_t){0.f,0.f,0.f,0.f}, 0, 0, 0);
            ak0 = __builtin_amdgcn_mfma_f32_16x16x32_bf16(af1, bk01, ak0, 0, 0, 0);
            f32x4_t ak1 = __builtin_amdgcn_mfma_f32_16x16x32_bf16(af0, bk10, (f32x4_t){0.f,0.f,0.f,0.f}, 0, 0, 0);
            ak1 = __builtin_amdgcn_mfma_f32_16x16x32_bf16(af1, bk11, ak1, 0, 0, 0);
            f32x4_t av0 = __builtin_amdgcn_mfma_f32_16x16x32_bf16(af0, bv00, (f32x4_t){0.f,0.f,0.f,0.f}, 0, 0, 0);
            av0 = __builtin_amdgcn_mfma_f32_16x16x32_bf16(af1, bv01, av0, 0, 0, 0);
            f32x4_t av1 = __builtin_amdgcn_mfma_f32_16x16x32_bf16(af0, bv10, (f32x4_t){0.f,0.f,0.f,0.f}, 0, 0, 0);
            av1 = __builtin_amdgcn_mfma_f32_16x16x32_bf16(af1, bv11, av1, 0, 0, 0);
            #pragma unroll
            for (int rg = 0; rg < 4; ++rg) {
                const int tr = q4 * 4 + rg;
                q_lds[tr * 68 + c0]  = aq0[rg] + bqv0;
                q_lds[tr * 68 + c1]  = aq1[rg] + bqv1;
                ky_lds[tr * 68 + c0] = ak0[rg] + bkv0;
                ky_lds[tr * 68 + c1] = ak1[rg] + bkv1;
                v_lds[tr * 68 + c0]  = av0[rg] + bvv0;
                v_lds[tr * 68 + c1]  = av1[rg] + bvv1;
            }
        }
        LOADM2(st * 5 + 3, f100, f101, f110, f111);   // F1 frags under attention
        __syncthreads();                   // B2: q/ky/v full

        // ---- attention core: 4 tokens/wave; 16-lane-group k-range reduce ----
        float kmax_t[4], kmin_t[4];
        {
            const int tg = wv * 4 + q4;    // group q4 owns token tg
            const float4 kv = *reinterpret_cast<const float4*>(&ky_lds[tg * 68 + lr * 4]);
            float kmx = fmaxf(fmaxf(kv.x, kv.y), fmaxf(kv.z, kv.w));
            float kmn = fminf(fminf(kv.x, kv.y), fminf(kv.z, kv.w));
            #pragma unroll
            for (int m = 1; m < 16; m <<= 1) {
                kmx = fmaxf(kmx, __shfl_xor(kmx, m, 64));
                kmn = fminf(kmn, __shfl_xor(kmn, m, 64));
            }
            #pragma unroll
            for (int tt = 0; tt < 4; ++tt) {
                kmax_t[tt] = __shfl(kmx, tt * 16, 64);
                kmin_t[tt] = __shfl(kmn, tt * 16, 64);
            }
        }
        #pragma unroll
        for (int tt = 0; tt < 4; ++tt) {
            const int t = wv * 4 + tt;
            const float qs = q_lds[t * 68 + l] * 1.44269504088896340736f;
            const float m2 = fmaxf(qs * kmax_t[tt], qs * kmin_t[tt]);   // exact row max (rank-1)
            const float* kb = &ky_lds[t * 68];
            const float* vb = &v_lds[t * 68];
            float s0 = 0.f, s1 = 0.f, p0 = 0.f, p1 = 0.f;
            #pragma unroll
            for (int j = 0; j < 64; j += 4) {
                const float4 kj = *reinterpret_cast<const float4*>(kb + j);   // uniform bcast
                const float4 vj = *reinterpret_cast<const float4*>(vb + j);
                const float e0 = fexp2(fmaf(qs, kj.x, -m2)); s0 += e0; p0 = fmaf(e0, vj.x, p0);
                const float e1 = fexp2(fmaf(qs, kj.y, -m2)); s1 += e1; p1 = fmaf(e1, vj.y, p1);
                const float e2v = fexp2(fmaf(qs, kj.z, -m2)); s0 += e2v; p0 = fmaf(e2v, vj.z, p0);
                const float e3 = fexp2(fmaf(qs, kj.w, -m2)); s1 += e3; p1 = fmaf(e3, vj.w, p1);
            }
            const float y = (p0 + p1) * frcp(s0 + s1) + cur_reg[tt];
            ky_lds[t * 68 + l] = y;        // own rows
        }
        LOADM2(st * 5 + 4, f200, f201, f210, f211);   // F2 frags
        __syncthreads();                   // B3: Y full

        // ---- F1: h1 = leaky(Y @ Wf1 + bf1, 0.01) -> a_lds bf16 (shared GEMM) ----
        {
            f32x4_t a0 = {0.f,0.f,0.f,0.f}, a1 = {0.f,0.f,0.f,0.f};
            #pragma unroll
            for (int kh = 0; kh < 2; ++kh) {
                const float* yp = &ky_lds[lr * 68 + kh * 32 + q4 * 8];
                const float4 y0 = *reinterpret_cast<const float4*>(yp);
                const float4 y1 = *reinterpret_cast<const float4*>(yp + 4);
                bfpack P;
                P.u[0] = pk2bf(y0.x, y0.y); P.u[1] = pk2bf(y0.z, y0.w);
                P.u[2] = pk2bf(y1.x, y1.y); P.u[3] = pk2bf(y1.z, y1.w);
                a0 = __builtin_amdgcn_mfma_f32_16x16x32_bf16(P.v, kh ? f101 : f100, a0, 0, 0, 0);
                a1 = __builtin_amdgcn_mfma_f32_16x16x32_bf16(P.v, kh ? f111 : f110, a1, 0, 0, 0);
            }
            #pragma unroll
            for (int rg = 0; rg < 4; ++rg) {
                const int tr = q4 * 4 + rg;
                float h0 = a0[rg] + bf1v0; h0 = h0 >= 0.f ? h0 : 0.01f * h0;
                float h1 = a1[rg] + bf1v1; h1 = h1 >= 0.f ? h1 : 0.01f * h1;
                a_lds[tr * 64 + (((c0 >> 3) ^ (tr & 7)) * 8) + (c0 & 7)] = f2bf(h0);
                a_lds[tr * 64 + (((c1 >> 3) ^ (tr & 7)) * 8) + (c1 & 7)] = f2bf(h1);
            }
        }
        __syncthreads();                   // B4: h1 full

        // ---- F2: A = h1 @ Wf2 + bf2 + Y -> ky_lds (shared GEMM) ----
        {
            const s16x8_t ag0 = *reinterpret_cast<const s16x8_t*>(&a_lds[lr * 64 + ((q4       ^ (lr & 7)) * 8)]);
            const s16x8_t ag1 = *reinterpret_cast<const s16x8_t*>(&a_lds[lr * 64 + (((4 + q4) ^ (lr & 7)) * 8)]);
            f32x4_t a0 = __builtin_amdgcn_mfma_f32_16x16x32_bf16(ag0, f200, (f32x4_t){0.f,0.f,0.f,0.f}, 0, 0, 0);
            a0 = __builtin_amdgcn_mfma_f32_16x16x32_bf16(ag1, f201, a0, 0, 0, 0);
            f32x4_t a1 = __builtin_amdgcn_mfma_f32_16x16x32_bf16(ag0, f210, (f32x4_t){0.f,0.f,0.f,0.f}, 0, 0, 0);
            a1 = __builtin_amdgcn_mfma_f32_16x16x32_bf16(ag1, f211, a1, 0, 0, 0);
            #pragma unroll
            for (int rg = 0; rg < 4; ++rg) {
                const int tr = q4 * 4 + rg;
                ky_lds[tr * 68 + c0] += a0[rg] + bf2v0;
                ky_lds[tr * 68 + c1] += a1[rg] + bf2v1;
            }
        }
        __syncthreads();                   // B5: A full

        // ---- next-stage QKV fragment loads (F frags dead; hides under LN) ----
        if (st < 2) {
            LOADM2((st + 1) * 5 + 0, bq00, bq01, bq10, bq11);
            LOADM2((st + 1) * 5 + 1, bk00, bk01, bk10, bk11);
            LOADM2((st + 1) * 5 + 2, bv00, bv01, bv10, bv11);
        }

        // ---- LayerNorm (16-lane groups, 4 tokens/wave) + residual ----
        {
            const int tg = wv * 4 + q4;
            const float4 av4 = *reinterpret_cast<const float4*>(&ky_lds[tg * 68 + lr * 4]);
            float ssum = av4.x + av4.y + av4.z + av4.w;
            #pragma unroll
            for (int m = 1; m < 16; m <<= 1) ssum += __shfl_xor(ssum, m, 64);
            const float mug = ssum * 0.015625f;
            const float d0 = av4.x - mug, d1 = av4.y - mug, d2 = av4.z - mug, d3 = av4.w - mug;
            float vsum = d0 * d0 + d1 * d1 + d2 * d2 + d3 * d3;
            #pragma unroll
            for (int m = 1; m < 16; m <<= 1) vsum += __shfl_xor(vsum, m, 64);
            #pragma unroll
            for (int tt = 0; tt < 4; ++tt) {
                const int t = wv * 4 + tt;
                const float mu = __shfl(mug, tt * 16, 64);
                const float vv = __shfl(vsum, tt * 16, 64);
                const float rs = frsq(vv * 0.015625f + 1e-5f);   // variance = vsum/64
                const float a  = ky_lds[t * 68 + l];
                const float an = (a - mu) * rs * lngv + lnbv;
                const float rnew = res_reg[tt] + an;
                res_reg[tt] = rnew;
                cur_reg[tt] = rnew;
                a_lds[t * 64 + (((l >> 3) ^ (t & 7)) * 8) + (l & 7)] = f2bf(rnew);
            }
        }
    }

    // ---------------- head: leaky(res @ Wout + bout, 0.1), 5 copies ----------------
    const float wo = Wout[l];
    const float bo = bout[0];
    #pragma unroll
    for (int tt = 0; tt < 4; ++tt)
        q_lds[(wv * 4 + tt) * 68 + l] = res_reg[tt] * wo;   // wave-private rows
    {
        const int tg = wv * 4 + q4;
        const float4 pv = *reinterpret_cast<const float4*>(&q_lds[tg * 68 + lr * 4]);
        float p = pv.x + pv.y + pv.z + pv.w;
        #pragma unroll
        for (int m = 1; m < 16; m <<= 1) p += __shfl_xor(p, m, 64);
        if (lr == 0) {
            float o = p + bo;
            o = o >= 0.f ? o : 0.1f * o;
            #pragma unroll
            for (int c5 = 0; c5 < 5; ++c5)
                out[(size_t)c5 * NTOK + n0 + tg] = o;
        }
    }
}

extern "C" void kernel_launch(void* const* d_in, const int* in_sizes, int n_in,
                              void* d_out, int out_size, void* d_ws, size_t ws_size,
                              hipStream_t stream) {
    const float* x    = (const float*)d_in[0];
    const float* W1   = (const float*)d_in[1];
    const float* b1   = (const float*)d_in[2];
    const float* Wq   = (const float*)d_in[3];
    const float* bq   = (const float*)d_in[4];
    const float* Wk   = (const float*)d_in[5];
    const float* bk   = (const float*)d_in[6];
    const float* Wv   = (const float*)d_in[7];
    const float* bv   = (const float*)d_in[8];
    const float* Wf1  = (const float*)d_in[9];
    const float* bf1  = (const float*)d_in[10];
    const float* Wf2  = (const float*)d_in[11];
    const float* bf2  = (const float*)d_in[12];
    const float* lngp = (const float*)d_in[13];
    const float* lnbp = (const float*)d_in[14];
    const float* Wout = (const float*)d_in[15];
    const float* bout = (const float*)d_in[16];
    float* outp = (float*)d_out;
    unsigned short* wsb = (unsigned short*)d_ws;

    hipLaunchKernelGGL(prep_kernel, dim3(304), dim3(256), 0, stream,
                       W1, Wq, Wk, Wv, Wf1, Wf2, wsb);
    hipLaunchKernelGGL(tf3_kernel, dim3(NTOK / TB), dim3(128), 0, stream,
                       x, b1, bq, bk, bv, bf1, bf2, lngp, lnbp, Wout, bout,
                       (const unsigned short*)wsb, outp);
}

// Round 17
// 56.378 us; speedup vs baseline: 1.3903x; 1.3903x over previous
//
#include <hip/hip_runtime.h>

#define NTOK 16384

typedef float f32x4_t __attribute__((ext_vector_type(4)));
typedef short s16x8_t __attribute__((ext_vector_type(8)));

union bfpack { unsigned int u[4]; s16x8_t v; };

__device__ __forceinline__ unsigned int pk2bf(float lo, float hi) {
    unsigned int r;
    asm("v_cvt_pk_bf16_f32 %0, %1, %2" : "=v"(r) : "v"(lo), "v"(hi));
    return r;
}
__device__ __forceinline__ unsigned short f2bf(float f) {
    unsigned int r;
    asm("v_cvt_pk_bf16_f32 %0, %1, %1" : "=v"(r) : "v"(f));
    return (unsigned short)r;
}
__device__ __forceinline__ unsigned short f2bf_host_style(float f) {
    unsigned int x = __float_as_uint(f);
    x += 0x7fffu + ((x >> 16) & 1u);
    return (unsigned short)(x >> 16);
}
__device__ __forceinline__ float fexp2(float x) {
#if __has_builtin(__builtin_amdgcn_exp2f)
    return __builtin_amdgcn_exp2f(x);
#else
    return exp2f(x);
#endif
}
__device__ __forceinline__ float frcp(float x) {
#if __has_builtin(__builtin_amdgcn_rcpf)
    return __builtin_amdgcn_rcpf(x);
#else
    return 1.0f / x;
#endif
}
__device__ __forceinline__ float frsq(float x) {
#if __has_builtin(__builtin_amdgcn_rsqf)
    return __builtin_amdgcn_rsqf(x);
#else
    return rsqrtf(x);
#endif
}

// ---- prep (R9/R10/R12-proven, unchanged): W1T [m][k] + attn weights in fragment order ----
// ushort off within matrix = hk*2048 + tile*512 + l*8 + e
//   holds W[k = hk*32 + (l>>4)*8 + e][m = tile*16 + (l&15)]
__global__ __launch_bounds__(256)
void prep_kernel(const float* __restrict__ W1,
                 const float* __restrict__ Wq, const float* __restrict__ Wk,
                 const float* __restrict__ Wv, const float* __restrict__ Wf1,
                 const float* __restrict__ Wf2, unsigned short* __restrict__ wsb)
{
    const int i = blockIdx.x * 256 + threadIdx.x;
    if (i < 16384) {
        const int m = i >> 8, k = i & 255;
        wsb[i] = f2bf_host_style(W1[k * 64 + m]);
    } else if (i < 77824) {
        const int u  = i - 16384;
        const int mi = u >> 12;            // matrix 0..14
        const int st = mi / 5, q = mi % 5;
        const int r  = u & 4095;
        const int hk = r >> 11;
        const int r1 = r & 2047;
        const int w  = r1 >> 9;
        const int r2 = r1 & 511;
        const int l  = r2 >> 3;
        const int e  = r2 & 7;
        const int m  = w * 16 + (l & 15);
        const int k  = hk * 32 + (l >> 4) * 8 + e;
        const float* src = q == 0 ? Wq : q == 1 ? Wk : q == 2 ? Wv : q == 3 ? Wf1 : Wf2;
        wsb[i] = f2bf_host_style(src[st * 4096 + k * 64 + m]);
    }
}

// 2-group software-pipelined kernel: 16 tokens/block as groups A (0..7) and B (8..15)
// with phases offset by 1 -> every barrier interval mixes MFMA/DS work of one group
// with the exp/VALU attention loop of the other. Phase bodies are R12-verbatim.
__global__ __launch_bounds__(256, 4)
void tf3_kernel(const float* __restrict__ x,
                const float* __restrict__ b1,
                const float* __restrict__ bq, const float* __restrict__ bk,
                const float* __restrict__ bv,
                const float* __restrict__ bf1, const float* __restrict__ bf2,
                const float* __restrict__ lng, const float* __restrict__ lnb,
                const float* __restrict__ Wout, const float* __restrict__ bout,
                const unsigned short* __restrict__ wsb,
                float* __restrict__ out)
{
    __shared__ __align__(16) char smem[30208];
    unsigned short* aA = (unsigned short*)smem;
    float* qA  = (float*)(smem + 2048);
    float* kyA = (float*)(smem + 6400);
    float* vA  = (float*)(smem + 10752);
    char*  xA  = smem + 2048;                   // stage0 image aliases qA∪kyA
    unsigned short* aB = (unsigned short*)(smem + 15104);
    float* qB  = (float*)(smem + 17152);
    float* kyB = (float*)(smem + 21504);
    float* vB  = (float*)(smem + 25856);
    char*  xB  = smem + 17152;

    const int tid = threadIdx.x;
    const int wv  = tid >> 6;
    const int l   = tid & 63;
    const int n0  = blockIdx.x * 16;

    const int lr  = l & 15;
    const int q4  = l >> 4;
    const int c   = wv * 16 + lr;
    const int e2  = l & 31;
    const int th  = wv * 2 + (l >> 5);

    float resA[2], curA[2], resB[2], curB[2];

    auto LOADM = [&](int mat, s16x8_t& r0, s16x8_t& r1) {
        const char* gb = (const char*)(wsb + 16384 + mat * 4096) + wv * 1024 + l * 16;
        r0 = *reinterpret_cast<const s16x8_t*>(gb);
        r1 = *reinterpret_cast<const s16x8_t*>(gb + 4096);
    };
    auto mmd = [&](s16x8_t af0, s16x8_t af1, s16x8_t b0, s16x8_t b1) -> f32x4_t {
        f32x4_t acc = __builtin_amdgcn_mfma_f32_16x16x32_bf16(af0, b0, (f32x4_t){0.f,0.f,0.f,0.f}, 0, 0, 0);
        acc = __builtin_amdgcn_mfma_f32_16x16x32_bf16(af1, b1, acc, 0, 0, 0);
        return acc;
    };

    s16x8_t bq0, bq1, bk0, bk1, bv0, bv1;
    s16x8_t f10, f11, f20, f21;

    // ---- phase bodies (R12-verbatim, pointer-parameterized) ----
    auto QKVp = [&](unsigned short* ag, float* qg, float* kyg, float* vg,
                    float bqv, float bkv, float bvv) {
        const s16x8_t af0 = *reinterpret_cast<const s16x8_t*>(&ag[lr * 64 + ((q4       ^ (lr & 7)) * 8)]);
        const s16x8_t af1 = *reinterpret_cast<const s16x8_t*>(&ag[lr * 64 + (((4 + q4) ^ (lr & 7)) * 8)]);
        f32x4_t aq = mmd(af0, af1, bq0, bq1);
        f32x4_t ak = mmd(af0, af1, bk0, bk1);
        f32x4_t av = mmd(af0, af1, bv0, bv1);
        #pragma unroll
        for (int rg = 0; rg < 4; ++rg) {
            const int tr = q4 * 4 + rg;
            qg[tr * 68 + c]  = aq[rg] + bqv;
            kyg[tr * 68 + c] = ak[rg] + bkv;
            vg[tr * 68 + c]  = av[rg] + bvv;
        }
    };
    auto ATTp = [&](float* qg, float* kyg, float* vg, float (&cur)[2]) {
        float kmax_t[2], kmin_t[2];
        {
            const float2 kv = *reinterpret_cast<const float2*>(&kyg[th * 68 + e2 * 2]);
            float kmx = fmaxf(kv.x, kv.y);
            float kmn = fminf(kv.x, kv.y);
            #pragma unroll
            for (int m = 1; m < 32; m <<= 1) {
                kmx = fmaxf(kmx, __shfl_xor(kmx, m, 64));
                kmn = fminf(kmn, __shfl_xor(kmn, m, 64));
            }
            #pragma unroll
            for (int tt = 0; tt < 2; ++tt) {
                kmax_t[tt] = __shfl(kmx, tt * 32, 64);
                kmin_t[tt] = __shfl(kmn, tt * 32, 64);
            }
        }
        #pragma unroll
        for (int tt = 0; tt < 2; ++tt) {
            const int t = wv * 2 + tt;
            const float qs = qg[t * 68 + l] * 1.44269504088896340736f;
            const float m2 = fmaxf(qs * kmax_t[tt], qs * kmin_t[tt]);   // exact row max (rank-1)
            const float* kb = &kyg[t * 68];
            const float* vb = &vg[t * 68];
            float s0 = 0.f, s1 = 0.f, p0 = 0.f, p1 = 0.f;
            #pragma unroll
            for (int j = 0; j < 64; j += 4) {
                const float4 kj = *reinterpret_cast<const float4*>(kb + j);   // uniform bcast
                const float4 vj = *reinterpret_cast<const float4*>(vb + j);
                const float e0 = fexp2(fmaf(qs, kj.x, -m2)); s0 += e0; p0 = fmaf(e0, vj.x, p0);
                const float e1 = fexp2(fmaf(qs, kj.y, -m2)); s1 += e1; p1 = fmaf(e1, vj.y, p1);
                const float e2v = fexp2(fmaf(qs, kj.z, -m2)); s0 += e2v; p0 = fmaf(e2v, vj.z, p0);
                const float e3 = fexp2(fmaf(qs, kj.w, -m2)); s1 += e3; p1 = fmaf(e3, vj.w, p1);
            }
            const float y = (p0 + p1) * frcp(s0 + s1) + cur[tt];
            kyg[t * 68 + l] = y;
        }
    };
    auto F1p = [&](float* kyg, unsigned short* ag, float bf1v) {
        f32x4_t acc = {0.f, 0.f, 0.f, 0.f};
        #pragma unroll
        for (int kh = 0; kh < 2; ++kh) {
            const float* yp = &kyg[lr * 68 + kh * 32 + q4 * 8];
            const float4 y0 = *reinterpret_cast<const float4*>(yp);
            const float4 y1 = *reinterpret_cast<const float4*>(yp + 4);
            bfpack P;
            P.u[0] = pk2bf(y0.x, y0.y); P.u[1] = pk2bf(y0.z, y0.w);
            P.u[2] = pk2bf(y1.x, y1.y); P.u[3] = pk2bf(y1.z, y1.w);
            acc = __builtin_amdgcn_mfma_f32_16x16x32_bf16(P.v, kh ? f11 : f10, acc, 0, 0, 0);
        }
        #pragma unroll
        for (int rg = 0; rg < 4; ++rg) {
            const int tr = q4 * 4 + rg;
            float h = acc[rg] + bf1v;
            h = h >= 0.f ? h : 0.01f * h;
            ag[tr * 64 + (((c >> 3) ^ (tr & 7)) * 8) + (c & 7)] = f2bf(h);
        }
    };
    auto F2p = [&](unsigned short* ag, float* kyg, float bf2v) {
        const s16x8_t ag0 = *reinterpret_cast<const s16x8_t*>(&ag[lr * 64 + ((q4       ^ (lr & 7)) * 8)]);
        const s16x8_t ag1 = *reinterpret_cast<const s16x8_t*>(&ag[lr * 64 + (((4 + q4) ^ (lr & 7)) * 8)]);
        f32x4_t acc = mmd(ag0, ag1, f20, f21);
        #pragma unroll
        for (int rg = 0; rg < 4; ++rg) {
            const int tr = q4 * 4 + rg;
            kyg[tr * 68 + c] += acc[rg] + bf2v;
        }
    };
    auto LNp = [&](float* kyg, unsigned short* ag, float (&cur)[2], float (&res)[2],
                   float lngv, float lnbv) {
        const float2 av2 = *reinterpret_cast<const float2*>(&kyg[th * 68 + e2 * 2]);
        float ssum = av2.x + av2.y;
        #pragma unroll
        for (int m = 1; m < 32; m <<= 1) ssum += __shfl_xor(ssum, m, 64);
        const float mug = ssum * 0.015625f;
        const float d0 = av2.x - mug, d1 = av2.y - mug;
        float vsum = d0 * d0 + d1 * d1;
        #pragma unroll
        for (int m = 1; m < 32; m <<= 1) vsum += __shfl_xor(vsum, m, 64);
        #pragma unroll
        for (int tt = 0; tt < 2; ++tt) {
            const int t = wv * 2 + tt;
            const float mu = __shfl(mug, tt * 32, 64);
            const float vv = __shfl(vsum, tt * 32, 64);
            const float rs = frsq(vv * 0.015625f + 1e-5f);   // variance = vsum/64
            const float a  = kyg[t * 68 + l];
            const float an = (a - mu) * rs * lngv + lnbv;
            const float rnew = res[tt] + an;
            res[tt] = rnew;
            cur[tt] = rnew;
            ag[t * 64 + (((l >> 3) ^ (t & 7)) * 8) + (l & 7)] = f2bf(rnew);
        }
    };
    auto HEADp = [&](float* qg, float (&res)[2], int base) {
        const float wo = Wout[l];
        const float bo = bout[0];
        #pragma unroll
        for (int tt = 0; tt < 2; ++tt)
            qg[(wv * 2 + tt) * 68 + l] = res[tt] * wo;   // wave-private rows
        const float2 pv = *reinterpret_cast<const float2*>(&qg[th * 68 + e2 * 2]);
        float p = pv.x + pv.y;
        #pragma unroll
        for (int m = 1; m < 32; m <<= 1) p += __shfl_xor(p, m, 64);
        if (e2 == 0) {
            float o = p + bo;
            o = o >= 0.f ? o : 0.1f * o;
            #pragma unroll
            for (int c5 = 0; c5 < 5; ++c5)
                out[(size_t)c5 * NTOK + base + th] = o;
        }
    };

    // ---- prologue ----
    LOADM(0, bq0, bq1); LOADM(1, bk0, bk1); LOADM(2, bv0, bv1);

    {   // x-convert both groups -> swizzled bf16 images
        const int r  = tid >> 5;
        const int cc = tid & 31;
        const float* xpA = x + (size_t)(n0 + r) * 256 + cc * 8;
        const float* xpB = x + (size_t)(n0 + 8 + r) * 256 + cc * 8;
        const float4 a0 = *reinterpret_cast<const float4*>(xpA);
        const float4 a1 = *reinterpret_cast<const float4*>(xpA + 4);
        const float4 b0 = *reinterpret_cast<const float4*>(xpB);
        const float4 b1v = *reinterpret_cast<const float4*>(xpB + 4);
        bfpack PA, PB;
        PA.u[0] = pk2bf(a0.x, a0.y); PA.u[1] = pk2bf(a0.z, a0.w);
        PA.u[2] = pk2bf(a1.x, a1.y); PA.u[3] = pk2bf(a1.z, a1.w);
        PB.u[0] = pk2bf(b0.x, b0.y); PB.u[1] = pk2bf(b0.z, b0.w);
        PB.u[2] = pk2bf(b1v.x, b1v.y); PB.u[3] = pk2bf(b1v.z, b1v.w);
        const int off = r * 512 + ((cc ^ (r & 7)) << 4);
        *reinterpret_cast<s16x8_t*>(xA + off) = PA.v;
        *reinterpret_cast<s16x8_t*>(xB + off) = PB.v;
    }
    __syncthreads();

    // stage0 compute both (shared W1T B-fragments)
    f32x4_t accA = {0.f,0.f,0.f,0.f}, accB = {0.f,0.f,0.f,0.f};
    #pragma unroll
    for (int s5 = 0; s5 < 8; ++s5) {
        const s16x8_t bf = *reinterpret_cast<const s16x8_t*>(&wsb[c * 256 + s5 * 32 + q4 * 8]);
        const int off = lr * 512 + (((s5 * 4 + q4) ^ (lr & 7)) << 4);
        const s16x8_t afA = *reinterpret_cast<const s16x8_t*>(xA + off);
        const s16x8_t afB = *reinterpret_cast<const s16x8_t*>(xB + off);
        accA = __builtin_amdgcn_mfma_f32_16x16x32_bf16(afA, bf, accA, 0, 0, 0);
        accB = __builtin_amdgcn_mfma_f32_16x16x32_bf16(afB, bf, accB, 0, 0, 0);
    }
    __syncthreads();                       // x-images consumed
    {
        const float bb = b1[c];
        #pragma unroll
        for (int rg = 0; rg < 4; ++rg) {
            const int tr = q4 * 4 + rg;
            qA[tr * 68 + c] = accA[rg] + bb;
            qB[tr * 68 + c] = accB[rg] + bb;
        }
    }
    __syncthreads();
    #pragma unroll
    for (int tt = 0; tt < 2; ++tt) {       // cur/res both groups
        const int t = wv * 2 + tt;
        const float hA = qA[t * 68 + l];
        curA[tt] = hA;
        resA[tt] = hA >= 0.f ? hA : 0.1f * hA;
        aA[t * 64 + (((l >> 3) ^ (t & 7)) * 8) + (l & 7)] = f2bf(hA);
        const float hB = qB[t * 68 + l];
        curB[tt] = hB;
        resB[tt] = hB >= 0.f ? hB : 0.1f * hB;
        aB[t * 64 + (((l >> 3) ^ (t & 7)) * 8) + (l & 7)] = f2bf(hB);
    }

    // ---- pipelined stages ----
    for (int st = 0; st < 3; ++st) {
        const float bqv  = bq[st * 64 + c];
        const float bkv  = bk[st * 64 + c];
        const float bvv  = bv[st * 64 + c];
        const float bf1v = bf1[st * 64 + c];
        const float bf2v = bf2[st * 64 + c];
        const float lngv = lng[st * 64 + l];
        const float lnbv = lnb[st * 64 + l];

        __syncthreads();                   // opens p1
        // p1: LN_B(st-1) || QKV_A(st)
        if (st > 0)
            LNp(kyB, aB, curB, resB, lng[(st - 1) * 64 + l], lnb[(st - 1) * 64 + l]);
        QKVp(aA, qA, kyA, vA, bqv, bkv, bvv);
        __syncthreads();
        // p2: ATT_A || QKV_B ; load F1 frags
        LOADM(st * 5 + 3, f10, f11);
        QKVp(aB, qB, kyB, vB, bqv, bkv, bvv);
        ATTp(qA, kyA, vA, curA);
        __syncthreads();
        // p3: F1_A || ATT_B ; load F2 frags
        LOADM(st * 5 + 4, f20, f21);
        F1p(kyA, aA, bf1v);
        ATTp(qB, kyB, vB, curB);
        __syncthreads();
        // p4: F2_A || F1_B ; load next QKV frags
        if (st < 2) {
            LOADM((st + 1) * 5 + 0, bq0, bq1);
            LOADM((st + 1) * 5 + 1, bk0, bk1);
            LOADM((st + 1) * 5 + 2, bv0, bv1);
        }
        F2p(aA, kyA, bf2v);
        F1p(kyB, aB, bf1v);
        __syncthreads();
        // p5: LN_A || F2_B
        F2p(aB, kyB, bf2v);
        LNp(kyA, aA, curA, resA, lngv, lnbv);
    }
    __syncthreads();
    // drain: LN_B(st=2) + heads (head uses wave-private q rows only)
    LNp(kyB, aB, curB, resB, lng[2 * 64 + l], lnb[2 * 64 + l]);
    HEADp(qA, resA, n0);
    HEADp(qB, resB, n0 + 8);
}

extern "C" void kernel_launch(void* const* d_in, const int* in_sizes, int n_in,
                              void* d_out, int out_size, void* d_ws, size_t ws_size,
                              hipStream_t stream) {
    const float* x    = (const float*)d_in[0];
    const float* W1   = (const float*)d_in[1];
    const float* b1   = (const float*)d_in[2];
    const float* Wq   = (const float*)d_in[3];
    const float* bq   = (const float*)d_in[4];
    const float* Wk   = (const float*)d_in[5];
    const float* bk   = (const float*)d_in[6];
    const float* Wv   = (const float*)d_in[7];
    const float* bv   = (const float*)d_in[8];
    const float* Wf1  = (const float*)d_in[9];
    const float* bf1  = (const float*)d_in[10];
    const float* Wf2  = (const float*)d_in[11];
    const float* bf2  = (const float*)d_in[12];
    const float* lngp = (const float*)d_in[13];
    const float* lnbp = (const float*)d_in[14];
    const float* Wout = (const float*)d_in[15];
    const float* bout = (const float*)d_in[16];
    float* outp = (float*)d_out;
    unsigned short* wsb = (unsigned short*)d_ws;

    hipLaunchKernelGGL(prep_kernel, dim3(304), dim3(256), 0, stream,
                       W1, Wq, Wk, Wv, Wf1, Wf2, wsb);
    hipLaunchKernelGGL(tf3_kernel, dim3(NTOK / 16), dim3(256), 0, stream,
                       x, b1, bq, bk, bv, bf1, bf2, lngp, lnbp, Wout, bout,
                       (const unsigned short*)wsb, outp);
}